// Round 3
// 386.484 us; speedup vs baseline: 1.0024x; 1.0024x over previous
//
#include <hip/hip_runtime.h>

// ShiftingLayer: out = zeros(H,W); out[i + trunc(wr[i,j]), j + trunc(wc[i,j])] = x[i,j]
// (OOB targets dropped). H=4096, W=8192, fp32.
//
// Pass A (fused_place): each thread owns 8 float4 chunks. All 24 loads are
//   issued STREAM-GROUPED (8x from x, then 8x wr, then 8x wc -> 32KB burst
//   per stream per block), pinned above the consume loop with
//   __builtin_amdgcn_sched_barrier(0) so the compiler cannot sink them back
//   into per-chunk load->wait->store serialization (R0 build: VGPR_Count=28
//   proved the load batch was compiler-sunk; DRAM saw 1KB stream-interleaved
//   runs -> 2.38 TB/s HBM, 58% of achievable).
// Pass B (worklist_scatter): scatters only nonzero-shift elements (empty
//   for the bench inputs -> exits immediately). Grid 256 (grid-stride).
//
// R1/R2: "container failed twice" (no diagnostics). Inline-asm vf4
//   keep-alive replaced with sched_barrier(0) — same pinning, zero runtime
//   cost, removes the only novel construct in case the failure was
//   compile-side. If this fails identically, it's infra.
// R4 lesson (prev session): __builtin_nontemporal_store regressed streaming
//   stores ~10% (131 -> 146 us at identical traffic) — use plain stores.

constexpr int H = 4096;
constexpr int W = 8192;                         // 2^13
constexpr long long TOTAL  = (long long)H * W;  // 33,554,432
constexpr long long NCHUNK = TOTAL / 4;         // 8,388,608 float4 chunks
constexpr int BLOCK = 256;
constexpr int CPT   = 8;                        // chunks per thread (pass A)

typedef float vf4 __attribute__((ext_vector_type(4)));

// ---- worklist path -------------------------------------------------------

__global__ __launch_bounds__(64) void init_ws_kernel(unsigned* __restrict__ ws) {
    if (threadIdx.x == 0) ws[0] = 0u;           // d_ws is poisoned 0xAA each call
}

__global__ __launch_bounds__(BLOCK) void fused_place_kernel(
    const float* __restrict__ x,
    const float* __restrict__ wr,
    const float* __restrict__ wc,
    float* __restrict__ out,
    unsigned* __restrict__ ws_count,
    unsigned* __restrict__ ws_list)
{
    const long long chunk0 = (long long)blockIdx.x * (BLOCK * CPT) + threadIdx.x;

    vf4 xv[CPT], rv[CPT], cv[CPT];

    // Stream-grouped load issue: 8 consecutive 1KB wave-loads per stream
    // (32KB contiguous burst per stream at block granularity).
    #pragma unroll
    for (int u = 0; u < CPT; ++u) {
        const long long base = (chunk0 + (long long)u * BLOCK) * 4;
        xv[u] = *reinterpret_cast<const vf4*>(x + base);
    }
    #pragma unroll
    for (int u = 0; u < CPT; ++u) {
        const long long base = (chunk0 + (long long)u * BLOCK) * 4;
        rv[u] = *reinterpret_cast<const vf4*>(wr + base);
    }
    #pragma unroll
    for (int u = 0; u < CPT; ++u) {
        const long long base = (chunk0 + (long long)u * BLOCK) * 4;
        cv[u] = *reinterpret_cast<const vf4*>(wc + base);
    }

    // Scheduling fence: nothing moves across this point — all 24 loads
    // above are issued before any consume work below (rule #18 idiom;
    // zero runtime instructions).
    __builtin_amdgcn_sched_barrier(0);

    #pragma unroll
    for (int u = 0; u < CPT; ++u) {
        const long long chunk = chunk0 + (long long)u * BLOCK;
        const long long base  = chunk * 4;

        // C float->int cast truncates toward zero == jnp.trunc + astype(int32)
        int rs0 = (int)rv[u].x, rs1 = (int)rv[u].y,
            rs2 = (int)rv[u].z, rs3 = (int)rv[u].w;
        int cs0 = (int)cv[u].x, cs1 = (int)cv[u].y,
            cs2 = (int)cv[u].z, cs3 = (int)cv[u].w;

        if (((rs0 | rs1 | rs2 | rs3) | (cs0 | cs1 | cs2 | cs3)) == 0) {
            *reinterpret_cast<vf4*>(out + base) = xv[u];
        } else {
            vf4 ov;
            ov.x = ((rs0 | cs0) == 0) ? xv[u].x : 0.0f;
            ov.y = ((rs1 | cs1) == 0) ? xv[u].y : 0.0f;
            ov.z = ((rs2 | cs2) == 0) ? xv[u].z : 0.0f;
            ov.w = ((rs3 | cs3) == 0) ? xv[u].w : 0.0f;
            *reinterpret_cast<vf4*>(out + base) = ov;
            unsigned slot = atomicAdd(ws_count, 1u);   // device-scope default
            ws_list[slot] = (unsigned)chunk;
        }
    }
}

__global__ __launch_bounds__(BLOCK) void worklist_scatter_kernel(
    const float* __restrict__ x,
    const float* __restrict__ wr,
    const float* __restrict__ wc,
    float* __restrict__ out,
    const unsigned* __restrict__ ws_count,
    const unsigned* __restrict__ ws_list)
{
    const unsigned count  = ws_count[0];
    const unsigned stride = gridDim.x * blockDim.x;
    for (unsigned i = blockIdx.x * blockDim.x + threadIdx.x; i < count; i += stride) {
        long long base = (long long)ws_list[i] * 4;
        int row = (int)(base >> 13);
        int col = (int)(base & (W - 1));

        const vf4 xv = *reinterpret_cast<const vf4*>(x  + base);
        const vf4 rv = *reinterpret_cast<const vf4*>(wr + base);
        const vf4 cv = *reinterpret_cast<const vf4*>(wc + base);

        int rs, cs, tr, tc;
        rs = (int)rv.x; cs = (int)cv.x;
        if ((rs | cs) != 0) { tr = row + rs; tc = col + 0 + cs;
            if ((unsigned)tr < (unsigned)H && (unsigned)tc < (unsigned)W)
                out[(long long)tr * W + tc] = xv.x; }
        rs = (int)rv.y; cs = (int)cv.y;
        if ((rs | cs) != 0) { tr = row + rs; tc = col + 1 + cs;
            if ((unsigned)tr < (unsigned)H && (unsigned)tc < (unsigned)W)
                out[(long long)tr * W + tc] = xv.y; }
        rs = (int)rv.z; cs = (int)cv.z;
        if ((rs | cs) != 0) { tr = row + rs; tc = col + 2 + cs;
            if ((unsigned)tr < (unsigned)H && (unsigned)tc < (unsigned)W)
                out[(long long)tr * W + tc] = xv.z; }
        rs = (int)rv.w; cs = (int)cv.w;
        if ((rs | cs) != 0) { tr = row + rs; tc = col + 3 + cs;
            if ((unsigned)tr < (unsigned)H && (unsigned)tc < (unsigned)W)
                out[(long long)tr * W + tc] = xv.w; }
    }
}

// ---- fallback path (if d_ws too small): zero + full scatter --------------

__global__ __launch_bounds__(BLOCK) void zero_out_kernel(float* __restrict__ out) {
    long long tid = (long long)blockIdx.x * blockDim.x + threadIdx.x;
    vf4 z = {0.f, 0.f, 0.f, 0.f};
    *reinterpret_cast<vf4*>(out + tid * 4) = z;
}

__global__ __launch_bounds__(BLOCK) void shift_scatter_kernel(
    const float* __restrict__ x,
    const float* __restrict__ wr,
    const float* __restrict__ wc,
    float* __restrict__ out)
{
    long long tid  = (long long)blockIdx.x * blockDim.x + threadIdx.x;
    long long base = tid * 4;
    int row = (int)(base >> 13);
    int col = (int)(base & (W - 1));

    const vf4 xv = *reinterpret_cast<const vf4*>(x  + base);
    const vf4 rv = *reinterpret_cast<const vf4*>(wr + base);
    const vf4 cv = *reinterpret_cast<const vf4*>(wc + base);

    int rs0 = (int)rv.x, rs1 = (int)rv.y, rs2 = (int)rv.z, rs3 = (int)rv.w;
    int cs0 = (int)cv.x, cs1 = (int)cv.y, cs2 = (int)cv.z, cs3 = (int)cv.w;

    if (((rs0 | rs1 | rs2 | rs3) | (cs0 | cs1 | cs2 | cs3)) == 0) {
        *reinterpret_cast<vf4*>(out + base) = xv;
        return;
    }
    int tr, tc;
    tr = row + rs0; tc = col + 0 + cs0;
    if ((unsigned)tr < (unsigned)H && (unsigned)tc < (unsigned)W)
        out[(long long)tr * W + tc] = xv.x;
    tr = row + rs1; tc = col + 1 + cs1;
    if ((unsigned)tr < (unsigned)H && (unsigned)tc < (unsigned)W)
        out[(long long)tr * W + tc] = xv.y;
    tr = row + rs2; tc = col + 2 + cs2;
    if ((unsigned)tr < (unsigned)H && (unsigned)tc < (unsigned)W)
        out[(long long)tr * W + tc] = xv.z;
    tr = row + rs3; tc = col + 3 + cs3;
    if ((unsigned)tr < (unsigned)H && (unsigned)tc < (unsigned)W)
        out[(long long)tr * W + tc] = xv.w;
}

// ---- launch --------------------------------------------------------------

extern "C" void kernel_launch(void* const* d_in, const int* in_sizes, int n_in,
                              void* d_out, int out_size, void* d_ws, size_t ws_size,
                              hipStream_t stream) {
    const float* x  = (const float*)d_in[0];
    const float* wr = (const float*)d_in[1];
    const float* wc = (const float*)d_in[2];
    float* out = (float*)d_out;

    // worklist layout in d_ws: [0] counter (unsigned), [16..] chunk indices
    const size_t ws_needed = 16 + (size_t)NCHUNK * sizeof(unsigned);

    if (ws_size >= ws_needed) {
        unsigned* ws_count = (unsigned*)d_ws;
        unsigned* ws_list  = (unsigned*)((char*)d_ws + 16);
        const int grid = (int)(NCHUNK / (BLOCK * CPT));     // 4096 blocks
        init_ws_kernel<<<1, 64, 0, stream>>>(ws_count);
        fused_place_kernel<<<grid, BLOCK, 0, stream>>>(x, wr, wc, out,
                                                       ws_count, ws_list);
        worklist_scatter_kernel<<<256, BLOCK, 0, stream>>>(x, wr, wc, out,
                                                           ws_count, ws_list);
    } else {
        const int grid = (int)(NCHUNK / BLOCK);             // 32768 blocks
        zero_out_kernel<<<grid, BLOCK, 0, stream>>>(out);
        shift_scatter_kernel<<<grid, BLOCK, 0, stream>>>(x, wr, wc, out);
    }
}